// Round 6
// baseline (171.546 us; speedup 1.0000x reference)
//
#include <hip/hip_runtime.h>
#include <cstdint>
#include <cmath>

#define NROWS 8192
#define KDIM  512            // elements; also bytes/row in fp8
#define SLAB  ((size_t)16384 * 64)   // one k-major block: all 16384 rows x 64 B

typedef int    i32x4  __attribute__((ext_vector_type(4)));
typedef int    i32x8  __attribute__((ext_vector_type(8)));
typedef float  f32x16 __attribute__((ext_vector_type(16)));
typedef unsigned char u8;

// --- Kernel 1: row L2-normalize fp32 -> fp8 e4m3 (OCP, HW cvt), one wave/row.
// R17: output is K-MAJOR BLOCKED: buf[k0/64][row][64] (8 slabs of 1 MB).
// This makes the GEMM's direct-from-global fragment loads perfectly coalesced
// (a wave's 32x32x64-operand = one contiguous 2 KB burst). zi rows [0,8192),
// zj rows [8192,16384). Also zeroes the 128 accumulator slots.
__global__ __launch_bounds__(256) void nrm_kernel(const float* __restrict__ zi,
                                                  const float* __restrict__ zj,
                                                  u8* __restrict__ out,
                                                  double* __restrict__ acc) {
    if (blockIdx.x == 0 && threadIdx.x < 128) acc[threadIdx.x] = 0.0;
    const int wave = threadIdx.x >> 6;
    const int lane = threadIdx.x & 63;
    const int row  = blockIdx.x * 4 + wave;            // 0..16383
    const float* src = (row < NROWS) ? zi + (size_t)row * KDIM
                                     : zj + (size_t)(row - NROWS) * KDIM;
    float4 a = ((const float4*)src)[lane];             // elems [4l, 4l+4)
    float4 b = ((const float4*)src)[lane + 64];        // elems [4l+256, ..)
    float ss = a.x*a.x + a.y*a.y + a.z*a.z + a.w*a.w
             + b.x*b.x + b.y*b.y + b.z*b.z + b.w*b.w;
    #pragma unroll
    for (int off = 32; off >= 1; off >>= 1) ss += __shfl_xor(ss, off, 64);
    const float inv = 1.0f / fmaxf(sqrtf(ss), 1e-12f);
    int p0 = 0, p1 = 0;
    p0 = __builtin_amdgcn_cvt_pk_fp8_f32(a.x * inv, a.y * inv, p0, false);
    p0 = __builtin_amdgcn_cvt_pk_fp8_f32(a.z * inv, a.w * inv, p0, true);
    p1 = __builtin_amdgcn_cvt_pk_fp8_f32(b.x * inv, b.y * inv, p1, false);
    p1 = __builtin_amdgcn_cvt_pk_fp8_f32(b.z * inv, b.w * inv, p1, true);
    // k-byte 4*lane lives in slab lane>>4 at in-row offset (lane&15)*4;
    // k-byte 4*lane+256 is 4 slabs later, same in-row offset.
    u8* dst = out + (size_t)(lane >> 4) * SLAB + (size_t)row * 64 + (lane & 15) * 4;
    *(int*)dst            = p0;
    *(int*)(dst + 4 * SLAB) = p1;
}

// --- Kernel 2: fused MX-fp8 A*B^T -> exp(10*dot) -> global sum.
// R17: NO LDS IN THE K-LOOP. R11/R14/R15 schedule variants all pinned at
// 83+-2 us / MfmaUtil ~25% with a CONSTANT 4,767,744 bank-conflict count
// (= 4 extra cyc on every one of 1.19M ds_read_b128 — structural). Per
// block-step the LDS port carried ~770 cyc of conflicted reads + ~190 cyc
// staging writes vs ~550 cyc of MFMA: the port, not latency, was the limit
// (R16 showed geometry can't fix it either: 1 block/CU lost cross-block
// overlap, 101.8 us). The 8 MB operand set is L2/L3-resident (FETCH flat at
// 18.6 MB all rounds) — staging cached data through LDS was pure overhead
// (guide Common-mistake #7). Here each wave loads its MFMA fragments
// DIRECTLY global->VGPR from the k-major layout: lane l reads 32 B at
// (row = base + (l&31), k-bytes 32*(l>>5) + [0,32)) = one contiguous 2 KB
// burst per fragment. No barriers, no waitcnt asm, no swizzle, no staging:
// pure load->MFMA loop, the compiler's best-known scheduling regime, with
// 2 barrier-free blocks/CU (launch_bounds (256,2): 128 VGPR + 128 AGPR
// = 256 regs -> 2 waves/SIMD) anti-phasing loads against MFMAs.
// Triangle skip (R11-verified): pos = bx<64, skip bx<2by; bx>=2by+2 weight 2;
// near-diag pair bx>>1==by at weight 1 with per-element rr==cc skip.
// Relaxed atomicAdd + separate finalize (R12/R13 lesson: agent-scope acquire
// in-kernel = per-block L2 invalidate = 2x regression; never re-fuse).
__global__ __launch_bounds__(256, 2) void gemm_exp_reduce(const u8* __restrict__ A,
                                                          const u8* __restrict__ B,
                                                          double* __restrict__ acc) {
    const int bx = blockIdx.x, by = blockIdx.y;
    const bool pos = (bx < 64);
    if (pos && bx < 2 * by) return;   // strict lower-tri pos block: mirror elsewhere

    __shared__ float red[4];

    const int tid  = threadIdx.x;
    const int lane = tid & 63;
    const int wave = tid >> 6;
    const int m0   = by * 256;
    const int n0   = bx * 128;
    const int wm   = (wave >> 1) * 128;
    const int wn   = (wave & 1) * 64;

    f32x16 accf[4][2];
    #pragma unroll
    for (int i = 0; i < 4; ++i)
        #pragma unroll
        for (int j = 0; j < 2; ++j)
            #pragma unroll
            for (int r = 0; r < 16; ++r)
                accf[i][j][r] = 0.f;

    // per-lane offset inside a 32-row x 64-B fragment group (k-major layout):
    // row (lane&31) at stride 64, k-half (lane>>5)*32. One frag = 2 KB contig.
    const int lofs = (lane & 31) * 64 + (lane >> 5) * 32;
    const u8* pA = A + (size_t)(m0 + wm) * 64 + lofs;   // + kb*SLAB + mi*2048
    const u8* pB = B + (size_t)(n0 + wn) * 64 + lofs;   // + kb*SLAB + ni*2048

    #pragma unroll
    for (int kb = 0; kb < 8; ++kb) {       // 8 K-steps of 64 bytes
        const size_t ko = (size_t)kb * SLAB;
        i32x8 bfr[2], af[4];
        #pragma unroll
        for (int ni = 0; ni < 2; ++ni)
            bfr[ni] = *(const i32x8*)(pB + ko + (size_t)ni * 2048);
        #pragma unroll
        for (int mi = 0; mi < 4; ++mi)
            af[mi] = *(const i32x8*)(pA + ko + (size_t)mi * 2048);
        #pragma unroll
        for (int mi = 0; mi < 4; ++mi)
            #pragma unroll
            for (int ni = 0; ni < 2; ++ni)
                accf[mi][ni] = __builtin_amdgcn_mfma_scale_f32_32x32x64_f8f6f4(
                    af[mi], bfr[ni], accf[mi][ni],
                    0, 0,                 // cbsz=fp8(e4m3), blgp=fp8(e4m3)
                    0, 0x7f7f7f7f,        // scale_a: every byte = 2^0
                    0, 0x7f7f7f7f);       // scale_b
    }

    // epilogue: exp(10*d) = exp2(d*10/ln2); near-diag pos blocks skip rr==cc
    const float LOG2E10 = 14.4269504088896341f;
    const int r_ = lane & 31;
    const int q_ = lane >> 5;
    float part = 0.f;
    if (pos && (bx >> 1) == by) {
        #pragma unroll
        for (int mi = 0; mi < 4; ++mi)
            #pragma unroll
            for (int ni = 0; ni < 2; ++ni)
                #pragma unroll
                for (int r = 0; r < 16; ++r) {
                    // C/D 32x32: col=lane&31, row=(r&3)+8*(r>>2)+4*(lane>>5)
                    int rr = m0 + wm + mi * 32 + ((r & 3) + 8 * (r >> 2) + 4 * q_);
                    int cc = n0 + wn + ni * 32 + r_;
                    if (rr != cc) part += exp2f(accf[mi][ni][r] * LOG2E10);
                }
    } else {
        #pragma unroll
        for (int mi = 0; mi < 4; ++mi)
            #pragma unroll
            for (int ni = 0; ni < 2; ++ni)
                #pragma unroll
                for (int r = 0; r < 16; ++r)
                    part += exp2f(accf[mi][ni][r] * LOG2E10);
    }

    #pragma unroll
    for (int off = 32; off >= 1; off >>= 1) part += __shfl_xor(part, off, 64);
    if (lane == 0) red[wave] = part;
    __syncthreads();
    if (tid == 0) {
        double s = (double)red[0] + (double)red[1] + (double)red[2] + (double)red[3];
        if (pos && bx >= 2 * by + 2) s *= 2.0;   // stands in for its skipped mirror
        atomicAdd(&acc[(pos ? 0 : 64) + (((unsigned)bx * 7 + (unsigned)by) & 63)], s);
    }
}

// --- Kernel 3: loss = log1p(neg/pos), pos += exact diagonal 8192*e^10.
// 128 threads, one global load each; LDS reduce then scalar finish.
__global__ __launch_bounds__(128) void finalize(const double* __restrict__ acc,
                                                float* __restrict__ out) {
    __shared__ double sp[128];
    const int t = threadIdx.x;
    sp[t] = acc[t];
    __syncthreads();
    if (t == 0) {
        double p = 0.0, n = 0.0;
        #pragma unroll
        for (int i = 0; i < 64; ++i) { p += sp[i]; n += sp[64 + i]; }
        p += 8192.0 * exp(10.0);
        out[0] = (float)log1p(n / p);
    }
}

extern "C" void kernel_launch(void* const* d_in, const int* in_sizes, int n_in,
                              void* d_out, int out_size, void* d_ws, size_t ws_size,
                              hipStream_t stream) {
    const float* zi = (const float*)d_in[0];
    const float* zj = (const float*)d_in[1];
    u8* nrm = (u8*)d_ws;                                      // 8 slabs x 1 MB = 8 MB
    double* acc = (double*)((char*)d_ws + (size_t)16384 * 512);

    nrm_kernel<<<4096, 256, 0, stream>>>(zi, zj, nrm, acc);
    dim3 grid(128, 32);   // x: 16384/128 n-tiles, y: 8192/256 m-tiles
    gemm_exp_reduce<<<grid, 256, 0, stream>>>(nrm, nrm, acc);
    finalize<<<1, 128, 0, stream>>>(acc, (float*)d_out);
}

// Round 7
// 147.867 us; speedup vs baseline: 1.1601x; 1.1601x over previous
//
#include <hip/hip_runtime.h>
#include <cstdint>
#include <cmath>

#define NROWS 8192
#define KDIM  512            // elements; also bytes/row in fp8

typedef int    i32x4  __attribute__((ext_vector_type(4)));
typedef int    i32x8  __attribute__((ext_vector_type(8)));
typedef float  f32x16 __attribute__((ext_vector_type(16)));
typedef unsigned char u8;

#define AS1(p) ((const __attribute__((address_space(1))) void*)(p))
#define AS3(p) ((__attribute__((address_space(3))) void*)(p))

// --- Kernel 1: row L2-normalize fp32 -> fp8 e4m3 (OCP, HW cvt), one wave/row.
// zi rows [0,8192), zj rows [8192,16384). Also zeroes the 128 accumulator slots.
__global__ __launch_bounds__(256) void nrm_kernel(const float* __restrict__ zi,
                                                  const float* __restrict__ zj,
                                                  u8* __restrict__ out,
                                                  double* __restrict__ acc) {
    if (blockIdx.x == 0 && threadIdx.x < 128) acc[threadIdx.x] = 0.0;
    const int wave = threadIdx.x >> 6;
    const int lane = threadIdx.x & 63;
    const int row  = blockIdx.x * 4 + wave;            // 0..16383
    const float* src = (row < NROWS) ? zi + (size_t)row * KDIM
                                     : zj + (size_t)(row - NROWS) * KDIM;
    float4 a = ((const float4*)src)[lane];
    float4 b = ((const float4*)src)[lane + 64];
    float ss = a.x*a.x + a.y*a.y + a.z*a.z + a.w*a.w
             + b.x*b.x + b.y*b.y + b.z*b.z + b.w*b.w;
    #pragma unroll
    for (int off = 32; off >= 1; off >>= 1) ss += __shfl_xor(ss, off, 64);
    const float inv = 1.0f / fmaxf(sqrtf(ss), 1e-12f);
    int p0 = 0, p1 = 0;
    p0 = __builtin_amdgcn_cvt_pk_fp8_f32(a.x * inv, a.y * inv, p0, false);
    p0 = __builtin_amdgcn_cvt_pk_fp8_f32(a.z * inv, a.w * inv, p0, true);
    p1 = __builtin_amdgcn_cvt_pk_fp8_f32(b.x * inv, b.y * inv, p1, false);
    p1 = __builtin_amdgcn_cvt_pk_fp8_f32(b.z * inv, b.w * inv, p1, true);
    int* dst = (int*)(out + (size_t)row * KDIM);
    dst[lane]      = p0;
    dst[lane + 64] = p1;
}

// --- Kernel 2: fused MX-fp8 A*B^T -> exp(10*dot) -> global sum.
// R18 = R11's proven-best loop (BK=128 single-buffer 2-barrier, 82.9 us,
// absmax 0) + XCD-BAND BLOCK REMAP. Evidence from R11-R17: MFMA-busy is a
// CONSTANT ~21 us (= the ideal MFMA work) across every schedule/geometry/
// no-LDS variant, while the wall is ~3000 cyc/step of unhidden memory wait —
// and FETCH_SIZE shows 18.6 MB of HBM traffic for an 8 MB L2-fittable
// operand set. Diagnosis: with blocks spread uniformly over (bx,by), each
// XCD's instantaneous working set (~64 blocks x 192 KB ~ 12 MB) thrashes its
// 4 MB L2, so staging loads keep paying L3/HBM latency that a depth-2
// pipeline cannot hide. Fix (T1 done for residency, not just locality):
// dispatch is round-robin (XCD = bid&7, m09), so give each XCD a FIXED set
// of 16 bx columns (bx === xcd mod 8) walked by-row: its 1 MB B-band stays
// permanently L2-resident and each A-panel streams once per by per XCD
// (~40 MB total L3 traffic vs ~500 MB before). The mod-8 bx interleave also
// load-balances the triangle-skipped pos columns across XCDs (a contiguous
// band split would be 1.32x imbalanced). Bijection: bid = (bx&7) + 8*((bx>>3)
// + 16*by). Inner loop, swizzle, triangle logic byte-identical to R11.
// Lessons kept: no fused finalize (R12/R13: per-block agent-acquire = L2
// invalidate = 2x), no sched_barrier pinning, no runtime-indexed LDS bufs.
__global__ __launch_bounds__(256, 2) void gemm_exp_reduce(const u8* __restrict__ A,
                                                          const u8* __restrict__ B,
                                                          double* __restrict__ acc) {
    // XCD-band remap: xcd = bid&7 owns bx ∈ {xcd, xcd+8, ..., xcd+120},
    // processed in by-major order (slot>>4 = by, slot&15 = column index).
    const int bid = blockIdx.x + 128 * blockIdx.y;
    const int bx  = (bid & 7) + 8 * ((bid >> 3) & 15);
    const int by  = bid >> 7;
    const bool pos = (bx < 64);
    if (pos && bx < 2 * by) return;   // strict lower-tri pos block: mirror elsewhere

    __shared__ u8 lA[2][256 * 64];   // 2 k-halves x 16 KB (8 regions of 32r x 64B)
    __shared__ u8 lB[2][128 * 64];   // 2 k-halves x 8 KB  (4 regions)
    __shared__ float red[4];

    const int tid  = threadIdx.x;
    const int lane = tid & 63;
    const int wave = tid >> 6;
    const int m0   = by * 256;
    const int n0   = bx * 128;
    const int wm   = (wave >> 1) * 128;
    const int wn   = (wave & 1) * 64;

    f32x16 accf[4][2];
    #pragma unroll
    for (int i = 0; i < 4; ++i)
        #pragma unroll
        for (int j = 0; j < 2; ++j)
            #pragma unroll
            for (int r = 0; r < 16; ++r)
                accf[i][j][r] = 0.f;

    // staging (layout verified R2-R17): 16-row chunks of 1024 B per k-half.
    // A: wave does chunks wave*4..+3 (both halves); B: wave*2..+1.
    // lane: global row = chunk*16 + (lane>>2), 16B-col bsw = (lane&3)^((lane>>3)&3).
    const int bsw = (lane & 3) ^ ((lane >> 3) & 3);
    const u8* gA0 = A + (size_t)(m0 + wave * 64 + (lane >> 2)) * KDIM + bsw * 16;
    const u8* gB0 = B + (size_t)(n0 + wave * 32 + (lane >> 2)) * KDIM + bsw * 16;
    const int ldsA = wave * 4096 + lane * 16;
    const int ldsB = wave * 2048 + lane * 16;

    // fragment read: lane row r=lane&31, k-half-of-64 q=lane>>5 (chunks 2q,2q+1);
    // swizzled position p = r*4 + ((2q) ^ ((r>>1)&3)); partner chunk at ^16.
    const int r_  = lane & 31;
    const int q_  = lane >> 5;
    const int p16 = (r_ * 4 + ((2 * q_) ^ ((r_ >> 1) & 3))) * 16;
    const int aT0 = (wave >> 1) * 4;   // A regions aT0..aT0+3 (128 rows)
    const int bT0 = (wave & 1) * 2;    // B regions bT0..bT0+1 (64 rows)

    for (int k0 = 0; k0 < KDIM; k0 += 128) {   // BK=128: 4 iters, 8 barriers total
        __syncthreads();   // previous iteration's ds_reads done before overwrite
        #pragma unroll
        for (int h = 0; h < 2; ++h) {
            const size_t kb = (size_t)k0 + h * 64;
            #pragma unroll
            for (int c = 0; c < 4; ++c)
                __builtin_amdgcn_global_load_lds(AS1(gA0 + kb + (size_t)c * 16 * KDIM),
                                                 AS3(&lA[h][ldsA + c * 1024]), 16, 0, 0);
            #pragma unroll
            for (int c = 0; c < 2; ++c)
                __builtin_amdgcn_global_load_lds(AS1(gB0 + kb + (size_t)c * 16 * KDIM),
                                                 AS3(&lB[h][ldsB + c * 1024]), 16, 0, 0);
        }
        __syncthreads();   // vmcnt drain + barrier: both k-halves ready

        #pragma unroll
        for (int h = 0; h < 2; ++h) {   // 16 MFMAs between barrier pairs
            i32x8 af[4], bfr[2];
            #pragma unroll
            for (int mi = 0; mi < 4; ++mi) {
                const int off = (aT0 + mi) * 2048 + p16;
                *(i32x4*)&af[mi]       = *(const i32x4*)&lA[h][off];
                *((i32x4*)&af[mi] + 1) = *(const i32x4*)&lA[h][off ^ 16];
            }
            #pragma unroll
            for (int ni = 0; ni < 2; ++ni) {
                const int off = (bT0 + ni) * 2048 + p16;
                *(i32x4*)&bfr[ni]       = *(const i32x4*)&lB[h][off];
                *((i32x4*)&bfr[ni] + 1) = *(const i32x4*)&lB[h][off ^ 16];
            }
            #pragma unroll
            for (int mi = 0; mi < 4; ++mi)
                #pragma unroll
                for (int ni = 0; ni < 2; ++ni)
                    accf[mi][ni] = __builtin_amdgcn_mfma_scale_f32_32x32x64_f8f6f4(
                        af[mi], bfr[ni], accf[mi][ni],
                        0, 0,                 // cbsz=fp8(e4m3), blgp=fp8(e4m3)
                        0, 0x7f7f7f7f,        // scale_a: every byte = 2^0
                        0, 0x7f7f7f7f);       // scale_b
        }
    }

    // epilogue: exp(10*d) = exp2(d*10/ln2); near-diag pos blocks skip rr==cc
    const float LOG2E10 = 14.4269504088896341f;
    float part = 0.f;
    if (pos && (bx >> 1) == by) {
        #pragma unroll
        for (int mi = 0; mi < 4; ++mi)
            #pragma unroll
            for (int ni = 0; ni < 2; ++ni)
                #pragma unroll
                for (int r = 0; r < 16; ++r) {
                    // C/D 32x32: col=lane&31, row=(r&3)+8*(r>>2)+4*(lane>>5)
                    int rr = m0 + wm + mi * 32 + ((r & 3) + 8 * (r >> 2) + 4 * q_);
                    int cc = n0 + wn + ni * 32 + r_;
                    if (rr != cc) part += exp2f(accf[mi][ni][r] * LOG2E10);
                }
    } else {
        #pragma unroll
        for (int mi = 0; mi < 4; ++mi)
            #pragma unroll
            for (int ni = 0; ni < 2; ++ni)
                #pragma unroll
                for (int r = 0; r < 16; ++r)
                    part += exp2f(accf[mi][ni][r] * LOG2E10);
    }

    #pragma unroll
    for (int off = 32; off >= 1; off >>= 1) part += __shfl_xor(part, off, 64);
    if (lane == 0) red[wave] = part;
    __syncthreads();
    if (tid == 0) {
        double s = (double)red[0] + (double)red[1] + (double)red[2] + (double)red[3];
        if (pos && bx >= 2 * by + 2) s *= 2.0;   // stands in for its skipped mirror
        atomicAdd(&acc[(pos ? 0 : 64) + (((unsigned)bx * 7 + (unsigned)by) & 63)], s);
    }
}

// --- Kernel 3: loss = log1p(neg/pos), pos += exact diagonal 8192*e^10.
// 128 threads, one global load each; LDS reduce then scalar finish.
__global__ __launch_bounds__(128) void finalize(const double* __restrict__ acc,
                                                float* __restrict__ out) {
    __shared__ double sp[128];
    const int t = threadIdx.x;
    sp[t] = acc[t];
    __syncthreads();
    if (t == 0) {
        double p = 0.0, n = 0.0;
        #pragma unroll
        for (int i = 0; i < 64; ++i) { p += sp[i]; n += sp[64 + i]; }
        p += 8192.0 * exp(10.0);
        out[0] = (float)log1p(n / p);
    }
}

extern "C" void kernel_launch(void* const* d_in, const int* in_sizes, int n_in,
                              void* d_out, int out_size, void* d_ws, size_t ws_size,
                              hipStream_t stream) {
    const float* zi = (const float*)d_in[0];
    const float* zj = (const float*)d_in[1];
    u8* nrm = (u8*)d_ws;                                      // [16384][512] fp8 = 8 MB
    double* acc = (double*)((char*)d_ws + (size_t)16384 * 512);

    nrm_kernel<<<4096, 256, 0, stream>>>(zi, zj, nrm, acc);
    dim3 grid(128, 32);   // x: 16384/128 n-tiles, y: 8192/256 m-tiles
    gemm_exp_reduce<<<grid, 256, 0, stream>>>(nrm, nrm, acc);
    finalize<<<1, 128, 0, stream>>>(acc, (float*)d_out);
}